// Round 5
// baseline (148.154 us; speedup 1.0000x reference)
//
#include <hip/hip_runtime.h>
#include <math.h>

#define N_NODES 50000
#define N_EDGES 1600000
#define IN_SIZE 128
#define HD 128          // NUM_HEADS * OUT_SIZE
#define NUM_HEADS 4
#define OUT_SIZE 32
#define STRIPS (N_NODES / 16)        // 3125 16-row strips
#define STRIPS_PER_WAVE 3
#define PROJ_WAVES ((STRIPS + STRIPS_PER_WAVE - 1) / STRIPS_PER_WAVE)   // 1042
#define PROJ_BLOCKS ((PROJ_WAVES + 3) / 4)                               // 261
#define OFF_BLOCKS ((N_NODES + 1 + 255) / 256)                           // 196
#define EDGE_BLOCKS ((N_NODES + 3) / 4)                                  // 12500

// 1/sqrt(32) * log2(e): base-2 softmax (exact reformulation)
#define SCALE2 0.25503486f

typedef _Float16 half8 __attribute__((ext_vector_type(8)));
typedef _Float16 half2v __attribute__((ext_vector_type(2)));
typedef __attribute__((ext_vector_type(4))) float floatx4;

static __device__ __forceinline__ half2v pk_f16(float a, float b) {
#if __has_builtin(__builtin_amdgcn_cvt_pkrtz)
    auto r = __builtin_amdgcn_cvt_pkrtz(a, b);         // v_cvt_pkrtz_f16_f32
    union { decltype(r) i; half2v o; } u;
    u.i = r;
    return u.o;
#else
    half2v r; r.x = (_Float16)a; r.y = (_Float16)b; return r;
#endif
}

static __device__ __forceinline__ float dot2(half2v a, half2v b, float c) {
#if __has_builtin(__builtin_amdgcn_fdot2)
    return __builtin_amdgcn_fdot2(a, b, c, false);     // v_dot2_f32_f16
#else
    return fmaf((float)a.x, (float)b.x, fmaf((float)a.y, (float)b.y, c));
#endif
}

static __device__ __forceinline__ half2v shflxor_h2(half2v x, int m) {
    union { half2v h; int i; } u; u.h = x;
    u.i = __shfl_xor(u.i, m);
    return u.h;
}

// ---------------------------------------------------------------------------
// K_pre v1 + head-split layout: fused projection + CSR offsets.
// hb is reorganized as [2][N][64] f16: half0 = dims 0..63 (heads 0,1),
// half1 = dims 64..127 (heads 2,3). Each half is 6.4 MB — the per-pass
// k_edge working set, targeted at the 4 MiB/XCD L2.
// Blocks [PROJ_BLOCKS, ...): off[n] = lower_bound(dst, n).
// ---------------------------------------------------------------------------
__global__ __launch_bounds__(256, 1) void k_pre(const float* __restrict__ feat,
                                                const float* __restrict__ W,
                                                const int* __restrict__ dst,
                                                _Float16* __restrict__ hb,
                                                int* __restrict__ off) {
    if (blockIdx.x >= PROJ_BLOCKS) {
        int i = (blockIdx.x - PROJ_BLOCKS) * 256 + threadIdx.x;
        if (i <= N_NODES) {
            int lo = 0, hi = N_EDGES;
            while (lo < hi) {
                int mid = (lo + hi) >> 1;
                if (dst[mid] < i) lo = mid + 1; else hi = mid;
            }
            off[i] = lo;
        }
        return;
    }

    int wid = blockIdx.x * 4 + (threadIdx.x >> 6);
    int lane = threadIdx.x & 63;
    int s0 = wid * STRIPS_PER_WAVE;
    if (s0 >= STRIPS) return;
    int quad = lane >> 4;
    int l15 = lane & 15;

    // B fragments: Bf[t][kb] = f16(W[kb*32+quad*8+j][t*16+l15]), j=0..7
    half8 Bf[8][4];
#pragma unroll
    for (int t = 0; t < 8; t++) {
#pragma unroll
        for (int kb = 0; kb < 4; kb++) {
            union { half8 v; half2v h[4]; } bu;
#pragma unroll
            for (int jj = 0; jj < 4; jj++) {
                int k0 = kb * 32 + quad * 8 + 2 * jj;
                float lo = W[(size_t)k0 * HD + t * 16 + l15];
                float hi = W[(size_t)(k0 + 1) * HD + t * 16 + l15];
                bu.h[jj] = pk_f16(lo, hi);
            }
            Bf[t][kb] = bu.v;
        }
    }

    for (int it = 0; it < STRIPS_PER_WAVE; it++) {
        int strip = s0 + it;
        if (strip >= STRIPS) break;
        int row = strip * 16 + l15;

        const float* ab = feat + (size_t)row * IN_SIZE + quad * 8;
        float4 a[8];
#pragma unroll
        for (int kb = 0; kb < 4; kb++) {
            a[2 * kb]     = *(const float4*)(ab + kb * 32);
            a[2 * kb + 1] = *(const float4*)(ab + kb * 32 + 4);
        }

        floatx4 acc[8];
#pragma unroll
        for (int t = 0; t < 8; t++) acc[t] = (floatx4)(0.f);

#pragma unroll
        for (int kb = 0; kb < 4; kb++) {
            float4 x = a[2 * kb], y = a[2 * kb + 1];
            union { half8 v; half2v h[4]; } af;
            af.h[0] = pk_f16(x.x, x.y);
            af.h[1] = pk_f16(x.z, x.w);
            af.h[2] = pk_f16(y.x, y.y);
            af.h[3] = pk_f16(y.z, y.w);
#pragma unroll
            for (int t = 0; t < 8; t++)
                acc[t] = __builtin_amdgcn_mfma_f32_16x16x32_f16(af.v, Bf[t][kb], acc[t], 0, 0, 0);
        }

        // C/D: global col = t*16+l15 -> half = t>>2, col64 = (t&3)*16+l15
#pragma unroll
        for (int t = 0; t < 8; t++) {
#pragma unroll
            for (int r = 0; r < 4; r++) {
                int R = strip * 16 + quad * 4 + r;
                size_t addr = (size_t)(t >> 2) * ((size_t)N_NODES * 64)
                            + (size_t)R * 64 + (t & 3) * 16 + l15;
                hb[addr] = (_Float16)acc[t][r];
            }
        }
    }
}

// ---------------------------------------------------------------------------
// K_edge v12: head-split two-pass gather (run twice, stream-serialized).
// Each pass reads one 6.4 MB half of hb ([N][64] f16, row = 128 B = ONE
// L2 line) — targets the measured wall: 64% L2 hit on a 12.8 MB working
// set vs 4 MiB/XCD L2, 152 MB/dispatch fabric misses at ~3 TB/s.
// Layout: 8 streams (g) x 8 lanes (p); lane owns dims 8p..8p+7 (16 B) of
// the half-row; head = p>>2. One dwordx4 per edge per lane (was two).
// Gather core = v11's proven idiom: unconditional clamped-index loads,
// select-on-value, 32-edge double-buffered quads.
// Score: 4x v_dot2_f32_f16 chain + quad combine xor{1,2}. Aggregation:
// 4x v_pk_fma_f16. Epilogue: reduce-scatter xor{8,16,32} over 4 h2 words
// (keep word w = 2*(g&1)+((g>>1)&1)); lanes g<4 store one float2 each.
// Denominators per head are pass-local (head dims don't cross halves).
// ---------------------------------------------------------------------------
union U4 { uint4 v; half2v h[4]; };

static __device__ __forceinline__ void loadq(U4 (&d)[4], int qb, int e1, int g, int p, int n,
                                             const int* __restrict__ src,
                                             const uint4* __restrict__ h4h) {
#pragma unroll
    for (int j = 0; j < 4; j++) {
        int ee = qb + 8 * j + g;
        bool a = ee < e1;
        int sv = src[a ? ee : 0];          // unconditional load, clamped index
        int row = a ? sv : n;              // select on VALUE (keeps load hoisted)
        d[j].v = h4h[(size_t)row * 8 + p]; // 16 B: dims 8p..8p+7 of the half-row
    }
}

static __device__ __forceinline__ void procq(const U4 (&vv)[4], int qb, int e1, int g,
                                             const half2v (&hdc)[4], float& s,
                                             half2v (&acc2)[4]) {
#pragma unroll
    for (int j = 0; j < 4; j++) {
        bool valid = (qb + 8 * j + g) < e1;
        float p0 = dot2(vv[j].h[0], hdc[0], 0.f);
        float p1 = dot2(vv[j].h[1], hdc[1], 0.f);
        p0 = dot2(vv[j].h[2], hdc[2], p0);
        p1 = dot2(vv[j].h[3], hdc[3], p1);
        float pd = p0 + p1;
        pd += __shfl_xor(pd, 1);           // 4 lanes span the head's 32 dims
        pd += __shfl_xor(pd, 2);
        float w = valid ? __builtin_amdgcn_exp2f(pd) : 0.f;
        s += w;
        half2v wh = pk_f16(w, w);
#pragma unroll
        for (int d = 0; d < 4; d++) acc2[d] += vv[j].h[d] * wh;   // v_pk_fma_f16
    }
}

__global__ __launch_bounds__(256) void k_edge(const _Float16* __restrict__ hbh,
                                              const int* __restrict__ src,
                                              const int* __restrict__ off,
                                              float* __restrict__ outh) {
    int n = (blockIdx.x * 256 + threadIdx.x) >> 6;
    int lane = threadIdx.x & 63;
    if (n >= N_NODES) return;
    int e0 = off[n], e1 = off[n + 1];

    int g = lane >> 3;       // edge stream 0..7
    int p = lane & 7;        // dims 8p..8p+7 (head = p>>2 within this half)

    const uint4* h4h = (const uint4*)hbh;  // one half-row = 8 uint4 = 128 B
    U4 hdv;
    hdv.v = h4h[(size_t)n * 8 + p];
    half2v hdc[4];
    half2v sc2 = pk_f16(SCALE2, SCALE2);
#pragma unroll
    for (int d = 0; d < 4; d++) hdc[d] = hdv.h[d] * sc2;  // pre-scaled, log2 domain

    float s = 0.f;
    half2v acc2[4];
#pragma unroll
    for (int d = 0; d < 4; d++) acc2[d] = (half2v)(_Float16)0.f;

    U4 va[4], vb[4];
    loadq(va, e0, e1, g, p, n, src, h4h);  // 32 edges in flight immediately

    int qb = e0;
    while (qb < e1) {
        loadq(vb, qb + 32, e1, g, p, n, src, h4h);
        procq(va, qb, e1, g, hdc, s, acc2);
        qb += 32;
        if (qb >= e1) break;
        loadq(va, qb + 32, e1, g, p, n, src, h4h);
        procq(vb, qb, e1, g, hdc, s, acc2);
        qb += 32;
    }

    // ---- reduce-scatter over the 8 streams (xor 8, 16, 32), 4 h2 words ----
    bool o1 = (g & 1) != 0, o2 = (g & 2) != 0;
    half2v t0 = o1 ? acc2[2] : acc2[0];
    half2v t1 = o1 ? acc2[3] : acc2[1];
    half2v s0 = o1 ? acc2[0] : acc2[2];
    half2v s1 = o1 ? acc2[1] : acc2[3];
    t0 = t0 + shflxor_h2(s0, 8);
    t1 = t1 + shflxor_h2(s1, 8);
    half2v k2 = o2 ? t1 : t0;
    half2v s2 = o2 ? t0 : t1;
    k2 = k2 + shflxor_h2(s2, 16);
    half2v fin = k2 + shflxor_h2(k2, 32);  // g and g^4 hold the same word

    s += __shfl_xor(s, 8); s += __shfl_xor(s, 16); s += __shfl_xor(s, 32);
    float inv = (s > 0.f) ? 1.f / s : 0.f; // denom for head p>>2 (lane-local)

    if (g < 4) {
        int w = 2 * (g & 1) + ((g >> 1) & 1);   // word index 0..3 (bijective)
        int dim = 8 * p + 2 * w;                // dim within this half (0..63)
        float2 o;
        o.x = (float)fin.x * inv;
        o.y = (float)fin.y * inv;
        *(float2*)(outh + (size_t)n * HD + dim) = o;
    }
}

// ---------------------------------------------------------------------------
extern "C" void kernel_launch(void* const* d_in, const int* in_sizes, int n_in,
                              void* d_out, int out_size, void* d_ws, size_t ws_size,
                              hipStream_t stream) {
    const float* feat = (const float*)d_in[0];
    const int*   src  = (const int*)d_in[1];
    const int*   dst  = (const int*)d_in[2];
    const float* W    = (const float*)d_in[3];
    float* out = (float*)d_out;

    char* ws = (char*)d_ws;
    _Float16* hb = (_Float16*)ws;                      // 12.8 MB, [2][N][64]
    int* off = (int*)(ws + (size_t)N_NODES * HD * 2);  // ~200 KB

    k_pre<<<PROJ_BLOCKS + OFF_BLOCKS, 256, 0, stream>>>(feat, W, dst, hb, off);
    // Two stream-serialized passes: each touches one 6.4 MB half of hb.
    k_edge<<<EDGE_BLOCKS, 256, 0, stream>>>(hb, src, off, out);
    k_edge<<<EDGE_BLOCKS, 256, 0, stream>>>(hb + (size_t)N_NODES * 64, src, off, out + 64);
}

// Round 6
// 144.983 us; speedup vs baseline: 1.0219x; 1.0219x over previous
//
#include <hip/hip_runtime.h>
#include <math.h>

#define N_NODES 50000
#define N_EDGES 1600000
#define IN_SIZE 128
#define HD 128          // NUM_HEADS * OUT_SIZE
#define NUM_HEADS 4
#define OUT_SIZE 32
#define STRIPS (N_NODES / 16)        // 3125 16-row strips
#define STRIPS_PER_WAVE 3
#define PROJ_WAVES ((STRIPS + STRIPS_PER_WAVE - 1) / STRIPS_PER_WAVE)   // 1042
#define PROJ_BLOCKS ((PROJ_WAVES + 3) / 4)                               // 261
#define OFF_BLOCKS ((N_NODES + 1 + 255) / 256)                           // 196

// 1/sqrt(32) * log2(e): base-2 softmax (exact reformulation)
#define SCALE2 0.25503486f

typedef _Float16 half8 __attribute__((ext_vector_type(8)));
typedef _Float16 half2v __attribute__((ext_vector_type(2)));
typedef __attribute__((ext_vector_type(4))) float floatx4;

static __device__ __forceinline__ half2v pk_f16(float a, float b) {
#if __has_builtin(__builtin_amdgcn_cvt_pkrtz)
    auto r = __builtin_amdgcn_cvt_pkrtz(a, b);         // v_cvt_pkrtz_f16_f32
    union { decltype(r) i; half2v o; } u;
    u.i = r;
    return u.o;
#else
    half2v r; r.x = (_Float16)a; r.y = (_Float16)b; return r;
#endif
}

static __device__ __forceinline__ float dot2(half2v a, half2v b, float c) {
#if __has_builtin(__builtin_amdgcn_fdot2)
    return __builtin_amdgcn_fdot2(a, b, c, false);     // v_dot2_f32_f16
#else
    return fmaf((float)a.x, (float)b.x, fmaf((float)a.y, (float)b.y, c));
#endif
}

static __device__ __forceinline__ half2v shflxor_h2(half2v x, int m) {
    union { half2v h; int i; } u; u.h = x;
    u.i = __shfl_xor(u.i, m);
    return u.h;
}

// ---------------------------------------------------------------------------
// K_pre v1 (known-good): fused projection + CSR offsets.
// 1042 waves, 3 strips/wave, Bf (8x4 half8) in VGPRs, no LDS/barriers.
// Blocks [PROJ_BLOCKS, ...): off[n] = lower_bound(dst, n).
// ~12 us: near its floor (38 MB stream + 1.6 GFLOP MFMA); v9's occupancy
// split regressed (+7 us B-setup) — do not revisit.
// ---------------------------------------------------------------------------
__global__ __launch_bounds__(256, 1) void k_pre(const float* __restrict__ feat,
                                                const float* __restrict__ W,
                                                const int* __restrict__ dst,
                                                _Float16* __restrict__ hb,
                                                int* __restrict__ off) {
    if (blockIdx.x >= PROJ_BLOCKS) {
        int i = (blockIdx.x - PROJ_BLOCKS) * 256 + threadIdx.x;
        if (i <= N_NODES) {
            int lo = 0, hi = N_EDGES;
            while (lo < hi) {
                int mid = (lo + hi) >> 1;
                if (dst[mid] < i) lo = mid + 1; else hi = mid;
            }
            off[i] = lo;
        }
        return;
    }

    int wid = blockIdx.x * 4 + (threadIdx.x >> 6);
    int lane = threadIdx.x & 63;
    int s0 = wid * STRIPS_PER_WAVE;
    if (s0 >= STRIPS) return;
    int quad = lane >> 4;
    int l15 = lane & 15;

    // B fragments: Bf[t][kb] = f16(W[kb*32+quad*8+j][t*16+l15]), j=0..7
    half8 Bf[8][4];
#pragma unroll
    for (int t = 0; t < 8; t++) {
#pragma unroll
        for (int kb = 0; kb < 4; kb++) {
            union { half8 v; half2v h[4]; } bu;
#pragma unroll
            for (int jj = 0; jj < 4; jj++) {
                int k0 = kb * 32 + quad * 8 + 2 * jj;
                float lo = W[(size_t)k0 * HD + t * 16 + l15];
                float hi = W[(size_t)(k0 + 1) * HD + t * 16 + l15];
                bu.h[jj] = pk_f16(lo, hi);
            }
            Bf[t][kb] = bu.v;
        }
    }

    for (int it = 0; it < STRIPS_PER_WAVE; it++) {
        int strip = s0 + it;
        if (strip >= STRIPS) break;
        int row = strip * 16 + l15;

        const float* ab = feat + (size_t)row * IN_SIZE + quad * 8;
        float4 a[8];
#pragma unroll
        for (int kb = 0; kb < 4; kb++) {
            a[2 * kb]     = *(const float4*)(ab + kb * 32);
            a[2 * kb + 1] = *(const float4*)(ab + kb * 32 + 4);
        }

        floatx4 acc[8];
#pragma unroll
        for (int t = 0; t < 8; t++) acc[t] = (floatx4)(0.f);

#pragma unroll
        for (int kb = 0; kb < 4; kb++) {
            float4 x = a[2 * kb], y = a[2 * kb + 1];
            union { half8 v; half2v h[4]; } af;
            af.h[0] = pk_f16(x.x, x.y);
            af.h[1] = pk_f16(x.z, x.w);
            af.h[2] = pk_f16(y.x, y.y);
            af.h[3] = pk_f16(y.z, y.w);
#pragma unroll
            for (int t = 0; t < 8; t++)
                acc[t] = __builtin_amdgcn_mfma_f32_16x16x32_f16(af.v, Bf[t][kb], acc[t], 0, 0, 0);
        }

        // C/D: col = t*16+l15, row = strip*16 + quad*4 + r
#pragma unroll
        for (int t = 0; t < 8; t++) {
#pragma unroll
            for (int r = 0; r < 4; r++) {
                int R = strip * 16 + quad * 4 + r;
                hb[(size_t)R * HD + t * 16 + l15] = (_Float16)acc[t][r];
            }
        }
    }
}

// ---------------------------------------------------------------------------
// K_edge v11 (FINAL — best measured: 50.0 us, n=5, sigma 0.02):
// 8 streams (g) x 8 lanes (p); lane owns 32 B [32p,32p+32) of the 256 B
// row = 16 f16 dims of ONE head (h = p>>1). Depth-4 quad pipeline:
// prologue issues 32 edges (8 KB) back-to-back — the entire median node
// (deg~32) in flight at wave start; double-buffered quads for heavier
// nodes. Unconditional clamped-index loads + select-on-value (guarded
// array loads get sunk by the compiler — v10 regression). Reduce-scatter
// epilogue (7 packed-h2 + 3 scalar shuffles); all 64 lanes store float2.
//
// TERMINAL per 5-design sweep: MLP x2 (v11), line-touches /2 + working
// set /2 (v12) all neutral — binding constraint is the chip's random
// 256 B-row gather service (~8.2 TB/s effective on a 12.8 MB table,
// 64% L2 hit, ~3.5 TB/s fabric refill). fp8 payload fails the 0.024
// absmax budget (6% rel err x tail |h|~2.5 ~ 0.15).
// ---------------------------------------------------------------------------
union U8 { uint4 v[2]; half2v h[8]; };

static __device__ __forceinline__ void loadq(U8 (&d)[4], int qb, int e1, int g, int p, int n,
                                             const int* __restrict__ src,
                                             const uint4* __restrict__ h4) {
#pragma unroll
    for (int j = 0; j < 4; j++) {
        int ee = qb + 8 * j + g;
        bool a = ee < e1;
        int sv = src[a ? ee : 0];          // unconditional load, clamped index
        int row = a ? sv : n;              // select on VALUE (keeps load hoisted)
        const uint4* rp = h4 + (size_t)row * 16 + 2 * p;
        d[j].v[0] = rp[0];                 // bytes [32p, 32p+16)
        d[j].v[1] = rp[1];                 // bytes [32p+16, 32p+32)
    }
}

static __device__ __forceinline__ void procq(const U8 (&vv)[4], int qb, int e1, int g,
                                             const half2v (&hdc)[8], float& s,
                                             half2v (&acc2)[8]) {
#pragma unroll
    for (int j = 0; j < 4; j++) {
        bool valid = (qb + 8 * j + g) < e1;
        float p0 = dot2(vv[j].h[0], hdc[0], 0.f);
        float p1 = dot2(vv[j].h[1], hdc[1], 0.f);
        p0 = dot2(vv[j].h[2], hdc[2], p0);
        p1 = dot2(vv[j].h[3], hdc[3], p1);
        p0 = dot2(vv[j].h[4], hdc[4], p0);
        p1 = dot2(vv[j].h[5], hdc[5], p1);
        p0 = dot2(vv[j].h[6], hdc[6], p0);
        p1 = dot2(vv[j].h[7], hdc[7], p1);
        float pd = p0 + p1;
        pd += __shfl_xor(pd, 1);           // 2 lanes span the head's 32 dims
        float w = valid ? __builtin_amdgcn_exp2f(pd) : 0.f;
        s += w;
        half2v wh = pk_f16(w, w);
#pragma unroll
        for (int d = 0; d < 8; d++) acc2[d] += vv[j].h[d] * wh;   // v_pk_fma_f16
    }
}

__global__ __launch_bounds__(256) void k_edge(const _Float16* __restrict__ hb,
                                              const int* __restrict__ src,
                                              const int* __restrict__ off,
                                              float* __restrict__ out) {
    int n = (blockIdx.x * 256 + threadIdx.x) >> 6;
    int lane = threadIdx.x & 63;
    if (n >= N_NODES) return;
    int e0 = off[n], e1 = off[n + 1];

    int g = lane >> 3;       // edge stream 0..7
    int p = lane & 7;        // dims 16p..16p+15 (head = p>>1)

    const uint4* h4 = (const uint4*)hb;    // one h row = 16 uint4
    const uint4* hrow = h4 + (size_t)n * 16;
    U8 hdv;
    hdv.v[0] = hrow[2 * p];
    hdv.v[1] = hrow[2 * p + 1];
    half2v hdc[8];
    half2v sc2 = pk_f16(SCALE2, SCALE2);
#pragma unroll
    for (int d = 0; d < 8; d++) hdc[d] = hdv.h[d] * sc2;  // pre-scaled, log2 domain

    float s = 0.f;
    half2v acc2[8];
#pragma unroll
    for (int d = 0; d < 8; d++) acc2[d] = (half2v)(_Float16)0.f;

    U8 va[4], vb[4];
    loadq(va, e0, e1, g, p, n, src, h4);   // 32 edges in flight immediately

    int qb = e0;
    while (qb < e1) {
        loadq(vb, qb + 32, e1, g, p, n, src, h4);
        procq(va, qb, e1, g, hdc, s, acc2);
        qb += 32;
        if (qb >= e1) break;
        loadq(va, qb + 32, e1, g, p, n, src, h4);
        procq(vb, qb, e1, g, hdc, s, acc2);
        qb += 32;
    }

    // ---- reduce-scatter over the 8 streams (xor 8, 16, 32) ----
    bool o1 = (g & 1) != 0, o2 = (g & 2) != 0, o4 = (g & 4) != 0;
    half2v r1v[4];
#pragma unroll
    for (int j = 0; j < 4; j++) {
        half2v kp = o1 ? acc2[j + 4] : acc2[j];
        half2v sd = o1 ? acc2[j] : acc2[j + 4];
        r1v[j] = kp + shflxor_h2(sd, 8);
    }
    half2v r2v[2];
#pragma unroll
    for (int j = 0; j < 2; j++) {
        half2v kp = o2 ? r1v[j + 2] : r1v[j];
        half2v sd = o2 ? r1v[j] : r1v[j + 2];
        r2v[j] = kp + shflxor_h2(sd, 16);
    }
    half2v kp3 = o4 ? r2v[1] : r2v[0];
    half2v sd3 = o4 ? r2v[0] : r2v[1];
    half2v fin = kp3 + shflxor_h2(sd3, 32);

    s += __shfl_xor(s, 8); s += __shfl_xor(s, 16); s += __shfl_xor(s, 32);
    float inv = (s > 0.f) ? 1.f / s : 0.f;   // denom for head p>>1 (lane-local)

    // surviving word w: dims (16p+2w, 16p+2w+1) — bijective over g
    int w = 4 * (g & 1) + 2 * ((g >> 1) & 1) + ((g >> 2) & 1);
    int dim = 16 * p + 2 * w;
    float2 o;
    o.x = (float)fin.x * inv;
    o.y = (float)fin.y * inv;
    *(float2*)(out + (size_t)n * HD + dim) = o;
}

// ---------------------------------------------------------------------------
extern "C" void kernel_launch(void* const* d_in, const int* in_sizes, int n_in,
                              void* d_out, int out_size, void* d_ws, size_t ws_size,
                              hipStream_t stream) {
    const float* feat = (const float*)d_in[0];
    const int*   src  = (const int*)d_in[1];
    const int*   dst  = (const int*)d_in[2];
    const float* W    = (const float*)d_in[3];
    float* out = (float*)d_out;

    char* ws = (char*)d_ws;
    _Float16* hb = (_Float16*)ws;                      // 12.8 MB, [node][128]
    int* off = (int*)(ws + (size_t)N_NODES * HD * 2);  // ~200 KB

    k_pre<<<PROJ_BLOCKS + OFF_BLOCKS, 256, 0, stream>>>(feat, W, dst, hb, off);
    k_edge<<<(N_NODES + 3) / 4, 256, 0, stream>>>(hb, src, off, out);
}